// Round 4
// baseline (93.522 us; speedup 1.0000x reference)
//
#include <hip/hip_runtime.h>
#include <math.h>

#define B_ 2
#define C_ 96
#define L_ 4096
#define N_ 16
#define R_ 6
#define K_ 4
#define D38 38
#define D40 40   // padded weight stride (cols 38,39 = 0)

// ---------------------------------------------------------------------------
// Prep: blocks [0,60) transpose x_proj weights (K,38,C) -> (K,C,40) zero-pad;
//       blocks [60,60+B*C) do per-row 64x64 transpose of x -> xT.
// ---------------------------------------------------------------------------
__global__ __launch_bounds__(256) void prep_kernel(
    const float* __restrict__ w, const float* __restrict__ x,
    float* __restrict__ wt, float* __restrict__ xT)
{
    int blk = blockIdx.x;
    if (blk < 60) {
        int i = blk * 256 + threadIdx.x;
        if (i < K_ * C_ * D40) {
            int k   = i / (C_ * D40);
            int rem = i % (C_ * D40);
            int cc  = rem / D40;
            int dd  = rem % D40;
            wt[i] = (dd < D38) ? w[((size_t)k * D38 + dd) * C_ + cc] : 0.f;
        }
    } else {
        __shared__ float t[64][65];
        int bc = blk - 60;
        const float* src = x  + (size_t)bc * L_;
        float*       dst = xT + (size_t)bc * L_;
        int r0  = threadIdx.x >> 6;
        int col = threadIdx.x & 63;
        #pragma unroll
        for (int rr = 0; rr < 16; ++rr) {
            int row = rr * 4 + r0;
            t[row][col] = src[row * 64 + col];
        }
        __syncthreads();
        #pragma unroll
        for (int rr = 0; rr < 16; ++rr) {
            int row = rr * 4 + r0;
            dst[row * 64 + col] = t[col][row];
        }
    }
}

// ---------------------------------------------------------------------------
// Kernel 1: projection. Block 512 = (l0 64) x (dq 4 output-groups) x (ch 2
// c-reduction halves). Grid = B*K*(L/64) = 512 -> 4096 waves.
// ---------------------------------------------------------------------------
__global__ __launch_bounds__(512) void proj_kernel(
    const float* __restrict__ x,     // (B,C,L)
    const float* __restrict__ xT,    // (B,C,L) col-major order
    const float* __restrict__ wt,    // (K,C,40)
    const float* __restrict__ dpw,   // (K,C,R)
    const float* __restrict__ dpb,   // (K,C)
    float* __restrict__ ws_delta,    // (B,K,C,L)
    float* __restrict__ ws_Bm,       // (B,K,L,N)
    float* __restrict__ ws_Cm)       // (B,K,L,N)
{
    __shared__ float T2[2][64][41];

    int tile = blockIdx.x;           // 0..511
    int lt   = tile & 63;
    int bk   = tile >> 6;
    int k    = bk & 3;
    int b    = bk >> 2;
    int tid  = threadIdx.x;
    int l0   = tid & 63;
    int dq   = (tid >> 6) & 3;
    int ch   = tid >> 8;             // 0/1 c-half
    int base = dq * 10;              // groups 0-9,10-19,20-29,30-39 (38,39 pad)

    int l = lt * 64 + l0;
    int m = (k >= 2) ? (L_ - 1 - l) : l;
    const float* src = ((k & 1) ? xT : x) + (size_t)b * C_ * L_;
    const float* wk  = wt + (size_t)k * C_ * D40 + base;

    float acc[10];
    #pragma unroll
    for (int t = 0; t < 10; ++t) acc[t] = 0.f;

    int c0 = ch * 48;
    #pragma unroll 4
    for (int cc = 0; cc < 48; ++cc) {
        int c = c0 + cc;
        float xv = src[(size_t)c * L_ + m];
        const float* wc = wk + c * D40;
        #pragma unroll
        for (int t = 0; t < 10; ++t) acc[t] = fmaf(xv, wc[t], acc[t]);
    }

    #pragma unroll
    for (int t = 0; t < 10; ++t) T2[ch][l0][base + t] = acc[t];
    __syncthreads();

    // ---- B/C cooperative coalesced stores (each thread: one float4)
    {
        int lq  = tid >> 3;          // l 0..63
        int sub = tid & 7;
        int buf = sub >> 2;          // 0=B, 1=C
        int q   = sub & 3;
        int col = R_ + buf * 16 + 4 * q;
        float4 v = make_float4(T2[0][lq][col]     + T2[1][lq][col],
                               T2[0][lq][col + 1] + T2[1][lq][col + 1],
                               T2[0][lq][col + 2] + T2[1][lq][col + 2],
                               T2[0][lq][col + 3] + T2[1][lq][col + 3]);
        float* dst = buf ? ws_Cm : ws_Bm;
        *(float4*)(dst + ((size_t)bk * L_ + lt * 64 + lq) * N_ + 4 * q) = v;
    }

    // ---- delta projection + softplus; c = cc*8 + (ch*4+dq) wave-uniform
    float ar[R_];
    #pragma unroll
    for (int r = 0; r < R_; ++r) ar[r] = T2[0][l0][r] + T2[1][l0][r];
    const float* dwk = dpw + (size_t)k * C_ * R_;
    const float* dbk = dpb + (size_t)k * C_;
    float* dlt = ws_delta + (size_t)bk * C_ * L_ + lt * 64 + l0;
    int cq = ch * 4 + dq;
    #pragma unroll 2
    for (int cc = 0; cc < 12; ++cc) {
        int c = cc * 8 + cq;
        float s = dbk[c];
        const float* dc = dwk + c * R_;
        #pragma unroll
        for (int r = 0; r < R_; ++r) s = fmaf(ar[r], dc[r], s);
        float sp = fmaxf(s, 0.f) + log1pf(__expf(-fabsf(s)));
        dlt[(size_t)c * L_] = sp;
    }
}

// ---------------------------------------------------------------------------
// Kernel 2: selective scan. Block = 1024 threads (16 waves) per channel.
// Thread (g,q): chunk g = w*16+i owns 16 l's, n-quad q. Fast path exploits
// A[n] == -(n+1) (runtime-checked, slow fallback): 1 exp + powers vs 4 exps.
// Log-time inter-wave combine via wave-0 rescan.
// ---------------------------------------------------------------------------
#define SR 17    // padded row stride (16+1)

__global__ __launch_bounds__(1024, 8) void scan_kernel(
    const float* __restrict__ ws_delta,  // (B,K,C,L)
    const float* __restrict__ x,         // (B,C,L)
    const float* __restrict__ xT,        // (B,C,L)
    const float* __restrict__ ws_Bm,     // (B,K,L,N)
    const float* __restrict__ ws_Cm,     // (B,K,L,N)
    const float* __restrict__ A_log,     // (K*C, N)
    const float* __restrict__ Ds,        // (K*C)
    float* __restrict__ out)             // 4 x (B,C,L)
{
    __shared__ float s_d[16][16 * SR];
    __shared__ float s_u[16][16 * SR];
    __shared__ float s_wA[16][N_];
    __shared__ float s_wB[16][N_];

    int chn = blockIdx.x;                // (b*K + k)*C + c
    int c  = chn % C_;
    int k  = (chn / C_) % K_;
    int b  = chn / (C_ * K_);
    int bk = b * K_ + k;
    int d  = k * C_ + c;

    int tid  = threadIdx.x;
    int w    = tid >> 6;                 // wave 0..15
    int lane = tid & 63;
    int i    = lane >> 2;                // chunk-in-wave 0..15
    int q    = lane & 3;                 // n-quad
    int g    = w * 16 + i;               // global chunk 0..255

    // A values + fast-path check (A[n] ?= -(n+1))
    float A4[4];
    bool okl = true;
    #pragma unroll
    for (int e = 0; e < 4; ++e) {
        A4[e] = -__expf(A_log[(size_t)d * N_ + 4 * q + e]);
        okl &= (fabsf(A4[e] + (float)(4 * q + e + 1)) < 1e-3f);
    }
    int fast = __all(okl);

    // ---- stage delta + u (256 floats per wave, one float4 per lane)
    {
        int e   = lane * 4;
        int row = e >> 4, col = e & 15;
        const float* dp = ws_delta + (size_t)chn * L_ + w * 256;
        *(float4*)(s_d[w] + row * SR + col) = *(const float4*)(dp + e);
        const float* usrc = ((k & 1) ? xT : x) + ((size_t)b * C_ + c) * L_;
        if (k < 2) {
            *(float4*)(s_u[w] + row * SR + col) =
                *(const float4*)(usrc + w * 256 + e);
        } else {
            float4 v = *(const float4*)(usrc + (L_ - 4 - w * 256 - e));
            *(float4*)(s_u[w] + row * SR + col) = make_float4(v.w, v.z, v.y, v.x);
        }
    }
    __syncthreads();

    const float* sd = s_d[w] + i * SR;
    const float* su = s_u[w] + i * SR;
    const float* Bp = ws_Bm + (size_t)bk * L_ * N_ + 4 * q;
    const float* Cp = ws_Cm + (size_t)bk * L_ * N_ + 4 * q;
    size_t lb = (size_t)(g * 16) * N_;

    // ---- pass 1: chunk composite
    float Ac[4] = {1.f, 1.f, 1.f, 1.f};
    float Bc[4] = {0.f, 0.f, 0.f, 0.f};
    if (fast) {
        float Rc = 1.f;
        #pragma unroll 4
        for (int j = 0; j < 16; ++j) {
            float dl = sd[j], ul = su[j], du = dl * ul;
            float4 B4 = *(const float4*)(Bp + lb + j * N_);
            const float* Bl = (const float*)&B4;
            float r  = __expf(-dl);
            float r2 = r * r, r4 = r2 * r2, r8 = r4 * r4;
            float t0 = (q & 1) ? r4 : 1.f;
            float s0 = (q & 2) ? t0 * r8 : t0;
            float a0 = s0 * r, a1 = s0 * r2, a2 = a1 * r, a3 = s0 * r4;
            Bc[0] = fmaf(a0, Bc[0], du * Bl[0]);
            Bc[1] = fmaf(a1, Bc[1], du * Bl[1]);
            Bc[2] = fmaf(a2, Bc[2], du * Bl[2]);
            Bc[3] = fmaf(a3, Bc[3], du * Bl[3]);
            Rc *= r;
        }
        float R2 = Rc * Rc, R4 = R2 * R2, R8 = R4 * R4;
        float t0 = (q & 1) ? R4 : 1.f;
        float s0 = (q & 2) ? t0 * R8 : t0;
        Ac[0] = s0 * Rc; Ac[1] = s0 * R2; Ac[2] = Ac[1] * Rc; Ac[3] = s0 * R4;
    } else {
        #pragma unroll 4
        for (int j = 0; j < 16; ++j) {
            float dl = sd[j], ul = su[j], du = dl * ul;
            float4 B4 = *(const float4*)(Bp + lb + j * N_);
            const float* Bl = (const float*)&B4;
            #pragma unroll
            for (int e = 0; e < 4; ++e) {
                float a = __expf(dl * A4[e]);
                Bc[e] = fmaf(a, Bc[e], du * Bl[e]);
                Ac[e] *= a;
            }
        }
    }

    // ---- intra-wave inclusive scan over 16 chunks
    #pragma unroll
    for (int s = 1; s < 16; s <<= 1) {
        float pA[4], pB[4];
        #pragma unroll
        for (int e = 0; e < 4; ++e) {
            pA[e] = __shfl_up(Ac[e], 4 * s, 64);
            pB[e] = __shfl_up(Bc[e], 4 * s, 64);
        }
        if (i >= s) {
            #pragma unroll
            for (int e = 0; e < 4; ++e) {
                Bc[e] = fmaf(Ac[e], pB[e], Bc[e]);
                Ac[e] *= pA[e];
            }
        }
    }

    // ---- inter-wave: wave 0 rescans the 16 wave-composites (log-time)
    if (i == 15) {
        #pragma unroll
        for (int e = 0; e < 4; ++e) {
            s_wA[w][4 * q + e] = Ac[e];
            s_wB[w][4 * q + e] = Bc[e];
        }
    }
    __syncthreads();
    if (w == 0) {
        float wA[4], wB[4];
        #pragma unroll
        for (int e = 0; e < 4; ++e) {
            wA[e] = s_wA[i][4 * q + e];
            wB[e] = s_wB[i][4 * q + e];
        }
        #pragma unroll
        for (int s = 1; s < 16; s <<= 1) {
            float pA[4], pB[4];
            #pragma unroll
            for (int e = 0; e < 4; ++e) {
                pA[e] = __shfl_up(wA[e], 4 * s, 64);
                pB[e] = __shfl_up(wB[e], 4 * s, 64);
            }
            if (i >= s) {
                #pragma unroll
                for (int e = 0; e < 4; ++e) {
                    wB[e] = fmaf(wA[e], pB[e], wB[e]);
                    wA[e] *= pA[e];
                }
            }
        }
        #pragma unroll
        for (int e = 0; e < 4; ++e) s_wB[i][4 * q + e] = wB[e];
    }
    __syncthreads();

    // wave-incoming state (h0 = 0 -> only B-part needed)
    float h[4] = {0.f, 0.f, 0.f, 0.f};
    if (w > 0) {
        #pragma unroll
        for (int e = 0; e < 4; ++e) h[e] = s_wB[w - 1][4 * q + e];
    }
    // chunk-incoming: apply lane i-1's inclusive-within-wave composite
    {
        float pA[4], pB[4];
        #pragma unroll
        for (int e = 0; e < 4; ++e) {
            pA[e] = __shfl_up(Ac[e], 4, 64);
            pB[e] = __shfl_up(Bc[e], 4, 64);
        }
        if (i > 0) {
            #pragma unroll
            for (int e = 0; e < 4; ++e) h[e] = fmaf(pA[e], h[e], pB[e]);
        }
    }

    // ---- pass 2: apply + output
    float Dd = Ds[d];
    int osel = (k == 0) ? 0 : (k == 2) ? 1 : (k == 1) ? 2 : 3;
    float* ob = out + ((size_t)osel * B_ + b) * ((size_t)C_ * L_) + (size_t)c * L_;

    if (fast) {
        #pragma unroll 4
        for (int j = 0; j < 16; ++j) {
            float dl = sd[j], ul = su[j], du = dl * ul;
            float4 B4 = *(const float4*)(Bp + lb + j * N_);
            float4 C4 = *(const float4*)(Cp + lb + j * N_);
            const float* Bl = (const float*)&B4;
            const float* Cl = (const float*)&C4;
            float r  = __expf(-dl);
            float r2 = r * r, r4 = r2 * r2, r8 = r4 * r4;
            float t0 = (q & 1) ? r4 : 1.f;
            float s0 = (q & 2) ? t0 * r8 : t0;
            float a0 = s0 * r, a1 = s0 * r2, a2 = a1 * r, a3 = s0 * r4;
            h[0] = fmaf(a0, h[0], du * Bl[0]);
            h[1] = fmaf(a1, h[1], du * Bl[1]);
            h[2] = fmaf(a2, h[2], du * Bl[2]);
            h[3] = fmaf(a3, h[3], du * Bl[3]);
            float y = h[0] * Cl[0];
            y = fmaf(h[1], Cl[1], y);
            y = fmaf(h[2], Cl[2], y);
            y = fmaf(h[3], Cl[3], y);
            y += __shfl_xor(y, 1, 64);
            y += __shfl_xor(y, 2, 64);
            if (q == 0) {
                y = fmaf(Dd, ul, y);
                int l = g * 16 + j;
                int idx;
                if (k == 0)      idx = l;
                else if (k == 2) idx = L_ - 1 - l;
                else if (k == 1) idx = ((l & 63) << 6) | (l >> 6);
                else { int mm = L_ - 1 - l; idx = ((mm & 63) << 6) | (mm >> 6); }
                ob[idx] = y;
            }
        }
    } else {
        #pragma unroll 4
        for (int j = 0; j < 16; ++j) {
            float dl = sd[j], ul = su[j], du = dl * ul;
            float4 B4 = *(const float4*)(Bp + lb + j * N_);
            float4 C4 = *(const float4*)(Cp + lb + j * N_);
            const float* Bl = (const float*)&B4;
            const float* Cl = (const float*)&C4;
            float y = 0.f;
            #pragma unroll
            for (int e = 0; e < 4; ++e) {
                float a = __expf(dl * A4[e]);
                h[e] = fmaf(a, h[e], du * Bl[e]);
                y = fmaf(h[e], Cl[e], y);
            }
            y += __shfl_xor(y, 1, 64);
            y += __shfl_xor(y, 2, 64);
            if (q == 0) {
                y = fmaf(Dd, ul, y);
                int l = g * 16 + j;
                int idx;
                if (k == 0)      idx = l;
                else if (k == 2) idx = L_ - 1 - l;
                else if (k == 1) idx = ((l & 63) << 6) | (l >> 6);
                else { int mm = L_ - 1 - l; idx = ((mm & 63) << 6) | (mm >> 6); }
                ob[idx] = y;
            }
        }
    }
}

// ---------------------------------------------------------------------------
extern "C" void kernel_launch(void* const* d_in, const int* in_sizes, int n_in,
                              void* d_out, int out_size, void* d_ws, size_t ws_size,
                              hipStream_t stream) {
    const float* x     = (const float*)d_in[0];
    const float* xpw   = (const float*)d_in[1];
    const float* dpw   = (const float*)d_in[2];
    const float* dpb   = (const float*)d_in[3];
    const float* A_log = (const float*)d_in[4];
    const float* Ds    = (const float*)d_in[5];
    float* out = (float*)d_out;

    float* ws = (float*)d_ws;
    const size_t dL  = (size_t)B_ * K_ * C_ * L_;   // 3,145,728
    const size_t bcL = (size_t)B_ * K_ * L_ * N_;   //   524,288
    const size_t xL  = (size_t)B_ * C_ * L_;        //   786,432
    float* ws_delta = ws;
    float* ws_Bm    = ws_delta + dL;
    float* ws_Cm    = ws_Bm + bcL;
    float* ws_xT    = ws_Cm + bcL;
    float* ws_Wt    = ws_xT + xL;                   // K*C*40 = 15,360

    prep_kernel<<<60 + B_ * C_, 256, 0, stream>>>(xpw, x, ws_Wt, ws_xT);
    proj_kernel<<<B_ * K_ * (L_ / 64), 512, 0, stream>>>(
        x, ws_xT, ws_Wt, dpw, dpb, ws_delta, ws_Bm, ws_Cm);
    scan_kernel<<<B_ * K_ * C_, 1024, 0, stream>>>(
        ws_delta, x, ws_xT, ws_Bm, ws_Cm, A_log, Ds, out);
}